// Round 6
// baseline (736.428 us; speedup 1.0000x reference)
//
#include <hip/hip_runtime.h>
#include <hip/hip_bf16.h>

#define NB   8
#define CCH  256
#define KCH  128
#define SSP  4096

typedef unsigned short u16;
typedef __attribute__((ext_vector_type(8))) short  bfrag;  // 8 bf16 = 4 VGPRs
typedef __attribute__((ext_vector_type(4))) float  ffrag;  // 4 fp32 acc

#define MFMA16(a, b, c) __builtin_amdgcn_mfma_f32_16x16x32_bf16((a), (b), (c), 0, 0, 0)
// u16-index XOR swizzle: flips bits 3-5 (16B granule) by row&7 -> bank spread
#define SWZ(i, r) ((unsigned)(i) ^ ((((unsigned)(r)) & 7u) << 3))

__device__ __forceinline__ u16 f2b(float f) {            // fp32 -> bf16 RNE
    union { float f; unsigned u; } v; v.f = f;
    return (u16)((v.u + 0x7fffu + ((v.u >> 16) & 1u)) >> 16);
}

// ---------------------------------------------------------------------------
// K1: g and phi projections, MFMA, register-pipelined staging. (unchanged)
// ---------------------------------------------------------------------------
__global__ __launch_bounds__(256, 2) void proj_gp_kernel(
    const float* __restrict__ x,
    const float* __restrict__ Wg, const float* __restrict__ bg,
    const float* __restrict__ Wp, const float* __restrict__ bp,
    u16* __restrict__ G,   // [N,K,S] transposed
    u16* __restrict__ P)   // [N,S,K]
{
    __shared__ __align__(16) u16 sm[12800];
    const int tid  = threadIdx.x;
    const int wv   = tid >> 6;
    const int lane = tid & 63;
    const int quad = lane >> 4, l16 = lane & 15;
    const int bid  = blockIdx.x;
    const int n  = bid & 7;
    const int s0 = (bid >> 3) * 64;

    const ffrag zf = {0.f, 0.f, 0.f, 0.f};
    ffrag ga[8], pa[8];
#pragma unroll
    for (int kb = 0; kb < 8; kb++) { ga[kb] = zf; pa[kb] = zf; }

    float4 xreg[2], wgreg[4], wpreg[4];
#pragma unroll
    for (int i = 0; i < 2; i++) {
        int f = tid + i * 256;
        int c = f >> 4, s4 = (f & 15) * 4;
        xreg[i] = *(const float4*)&x[((size_t)n * CCH + c) * SSP + s0 + s4];
    }
#pragma unroll
    for (int i = 0; i < 4; i++) {
        int f = tid + i * 256;
        int k = f >> 3, co = (f & 7) * 4;
        wgreg[i] = *(const float4*)&Wg[k * CCH + co];
        wpreg[i] = *(const float4*)&Wp[k * CCH + co];
    }

    for (int c0 = 0; c0 < CCH; c0 += 32) {
        __syncthreads();
#pragma unroll
        for (int i = 0; i < 2; i++) {
            int f = tid + i * 256;
            int c = f >> 4, s4 = (f & 15) * 4;
            sm[(s4 + 0) * 40 + c] = f2b(xreg[i].x);
            sm[(s4 + 1) * 40 + c] = f2b(xreg[i].y);
            sm[(s4 + 2) * 40 + c] = f2b(xreg[i].z);
            sm[(s4 + 3) * 40 + c] = f2b(xreg[i].w);
        }
#pragma unroll
        for (int i = 0; i < 4; i++) {
            int f = tid + i * 256;
            int k = f >> 3, co = (f & 7) * 4;
            ushort4 g4 = {f2b(wgreg[i].x), f2b(wgreg[i].y), f2b(wgreg[i].z), f2b(wgreg[i].w)};
            ushort4 p4 = {f2b(wpreg[i].x), f2b(wpreg[i].y), f2b(wpreg[i].z), f2b(wpreg[i].w)};
            *(ushort4*)&sm[2560 + k * 40 + co] = g4;
            *(ushort4*)&sm[7680 + k * 40 + co] = p4;
        }
        if (c0 + 32 < CCH) {
#pragma unroll
            for (int i = 0; i < 2; i++) {
                int f = tid + i * 256;
                int c = f >> 4, s4 = (f & 15) * 4;
                xreg[i] = *(const float4*)&x[((size_t)n * CCH + c0 + 32 + c) * SSP + s0 + s4];
            }
#pragma unroll
            for (int i = 0; i < 4; i++) {
                int f = tid + i * 256;
                int k = f >> 3, co = (f & 7) * 4;
                wgreg[i] = *(const float4*)&Wg[k * CCH + c0 + 32 + co];
                wpreg[i] = *(const float4*)&Wp[k * CCH + c0 + 32 + co];
            }
        }
        __syncthreads();
        bfrag a = *(const bfrag*)&sm[(16 * wv + l16) * 40 + quad * 8];
#pragma unroll
        for (int kb = 0; kb < 8; kb++) {
            bfrag bgf = *(const bfrag*)&sm[2560 + (16 * kb + l16) * 40 + quad * 8];
            bfrag bpf = *(const bfrag*)&sm[7680 + (16 * kb + l16) * 40 + quad * 8];
            ga[kb] = MFMA16(a, bgf, ga[kb]);
            pa[kb] = MFMA16(a, bpf, pa[kb]);
        }
    }
#pragma unroll
    for (int kb = 0; kb < 8; kb++) {
        int k = l16 + 16 * kb;
        float bgv = bg[k], bpv = bp[k];
        int srow = s0 + 16 * wv + quad * 4;
        ushort4 g4 = {f2b(ga[kb][0] + bgv), f2b(ga[kb][1] + bgv),
                      f2b(ga[kb][2] + bgv), f2b(ga[kb][3] + bgv)};
        *(ushort4*)&G[(size_t)n * KCH * SSP + (size_t)k * SSP + srow] = g4;
#pragma unroll
        for (int r = 0; r < 4; r++)
            P[((size_t)n * SSP + srow + r) * KCH + k] = f2b(pa[kb][r] + bpv);
    }
}

// ---------------------------------------------------------------------------
// K2: fused theta-proj + flash attention + out-proj, all MFMA.
// Round-11: REVERT to the round-1 (known-good, 217us) math and staging;
// the swapped-QK^T/shfl-PV experiment (rounds 8-10) is abandoned (its
// 480 MB scratch-write stream was unreachable by source-level fixes).
// Single variable vs round 1: OCCUPANCY. 256-thread blocks (q-tile 64)
// with LDS regions aliased down to a declared 40 KB -> 4 blocks/CU
// (160/40), 16 waves/CU, 4 waves/SIMD (launch_bounds(256,4), VGPR<=128).
// Independent blocks overlap each other's barrier/vmcnt drains -> the
// latency-bound profile (MfmaUtil~13, VALU~14, HBM~3%) finally gets TLP.
// LDS map (u16 idx, 20480 total = 40 KB):
//   [0,8192):      QS (ph0 -> qf hoist) / KS [64t][128k] (t-loop) / YS (epi)
//   [8192,16384):  XT@8192+WT@10752 (ph0) / GT [128k][64t] (t-loop) /
//                  WO [64c][128k] (epi, Wo staged in 64-row quarters)
//   [16384,20480): PS [64q][64t] (t-loop)
// ---------------------------------------------------------------------------
__global__ __launch_bounds__(256, 4) void attn_fused_kernel(
    const float* __restrict__ x,
    const float* __restrict__ Wt, const float* __restrict__ bt,
    const u16* __restrict__ Pb,   // phi rows bf16 [N,S,K]
    const u16* __restrict__ Gt,   // g bf16 TRANSPOSED [N,K,S]
    const float* __restrict__ Wo, const float* __restrict__ bo,
    float* __restrict__ out)
{
    __shared__ __align__(16) u16 sm[20480];     // 40 KB
    const int tid  = threadIdx.x;
    const int wv   = tid >> 6;                  // 0..3
    const int lane = tid & 63;
    const int quad = lane >> 4, l16 = lane & 15;
    const int bid  = blockIdx.x;
    const int n    = bid & 7;
    const int q0   = (bid >> 3) * 64;
    // 1/sqrt(128) * log2(e): exp(s*scale) == exp2(s*qscale)
    const float qscale = 0.08838834764831845f * 1.4426950408889634f;
    const ffrag zf = {0.f, 0.f, 0.f, 0.f};

    const int KSb = 0, GTb = 8192, XTb = 8192, WTb = 10752, WOb = 8192, PSb = 16384;

    const u16* Pbase = Pb + (size_t)n * SSP * KCH;
    const u16* Gbase = Gt + (size_t)n * KCH * SSP;

    // ---- issue first K/G tile loads NOW; they complete during phase 0 ----
    uint4 kreg[4], greg[4];
#pragma unroll
    for (int i = 0; i < 4; i++) {
        int f = tid + i * 256;
        int row = f >> 4, c8 = (f & 15) * 8;
        kreg[i] = *(const uint4*)(Pbase + (size_t)row * KCH + c8);
    }
#pragma unroll
    for (int i = 0; i < 4; i++) {
        int f = tid + i * 256;
        int k = f >> 3, ch = f & 7;
        greg[i] = *(const uint4*)(Gbase + (size_t)k * SSP + ch * 8);
    }

    // ---------------- Phase 0: Qs = (theta(x)+bt)*qscale, bf16 ----------------
    {
        ffrag qa[8];
#pragma unroll
        for (int kb = 0; kb < 8; kb++) qa[kb] = zf;

        for (int c0 = 0; c0 < CCH; c0 += 32) {
#pragma unroll
            for (int i = 0; i < 2; i++) {
                int f = tid + i * 256;
                int c = f >> 4, s4 = (f & 15) * 4;
                float4 xv = *(const float4*)&x[((size_t)n * CCH + c0 + c) * SSP + q0 + s4];
                sm[XTb + (s4 + 0) * 40 + c] = f2b(xv.x);
                sm[XTb + (s4 + 1) * 40 + c] = f2b(xv.y);
                sm[XTb + (s4 + 2) * 40 + c] = f2b(xv.z);
                sm[XTb + (s4 + 3) * 40 + c] = f2b(xv.w);
            }
#pragma unroll
            for (int i = 0; i < 4; i++) {
                int f = tid + i * 256;
                int k = f >> 3, co = (f & 7) * 4;
                float4 wq4 = *(const float4*)&Wt[k * CCH + c0 + co];
                ushort4 q4 = {f2b(wq4.x), f2b(wq4.y), f2b(wq4.z), f2b(wq4.w)};
                *(ushort4*)&sm[WTb + k * 40 + co] = q4;
            }
            __syncthreads();
            bfrag aq = *(const bfrag*)&sm[XTb + (16 * wv + l16) * 40 + quad * 8];
#pragma unroll
            for (int kb = 0; kb < 8; kb++) {
                bfrag bw = *(const bfrag*)&sm[WTb + (16 * kb + l16) * 40 + quad * 8];
                qa[kb] = MFMA16(aq, bw, qa[kb]);
            }
            __syncthreads();
        }
#pragma unroll
        for (int kb = 0; kb < 8; kb++) {
            float btv = bt[l16 + 16 * kb];
#pragma unroll
            for (int r = 0; r < 4; r++) {
                int row = 16 * wv + quad * 4 + r;
                sm[SWZ(row * 128 + l16 + 16 * kb, row)] = f2b((qa[kb][r] + btv) * qscale);
            }
        }
        // QS rows are wave-private; in-wave LDS ordering suffices below.
    }

    // ---- hoist Q A-fragments (own rows, no barrier needed) ----
    bfrag qf[4];
#pragma unroll
    for (int kc = 0; kc < 4; kc++)
        qf[kc] = *(const bfrag*)&sm[SWZ((16 * wv + l16) * 128 + kc * 32 + quad * 8, l16)];

    // ---------------- Phase 1: flash attention over t-tiles ----------------
    ffrag O[8];
#pragma unroll
    for (int kb = 0; kb < 8; kb++) O[kb] = zf;
    float l_r[4] = {0.f, 0.f, 0.f, 0.f};

    for (int t0 = 0; t0 < SSP; t0 += 64) {
        __syncthreads();          // prev tile consumed; iter 0: all qf hoisted
        // ---- commit pipelined tile to LDS (swizzled) ----
#pragma unroll
        for (int i = 0; i < 4; i++) {
            int f = tid + i * 256;
            int row = f >> 4, c8 = (f & 15) * 8;
            *(uint4*)&sm[KSb + SWZ(row * 128 + c8, row)] = kreg[i];
        }
#pragma unroll
        for (int i = 0; i < 4; i++) {
            int f = tid + i * 256;
            int k = f >> 3, ch = f & 7;
            *(uint4*)&sm[GTb + SWZ(k * 64 + ch * 8, k)] = greg[i];
        }
        // ---- prefetch next tile (in flight across the whole compute) ----
        if (t0 + 64 < SSP) {
#pragma unroll
            for (int i = 0; i < 4; i++) {
                int f = tid + i * 256;
                int row = f >> 4, c8 = (f & 15) * 8;
                kreg[i] = *(const uint4*)(Pbase + (size_t)(t0 + 64 + row) * KCH + c8);
            }
#pragma unroll
            for (int i = 0; i < 4; i++) {
                int f = tid + i * 256;
                int k = f >> 3, ch = f & 7;
                greg[i] = *(const uint4*)(Gbase + (size_t)k * SSP + t0 + 64 + ch * 8);
            }
        }
        __syncthreads();                    // staging visible

        // ---- QK^T (Q from registers) ----
        ffrag sa[4];
#pragma unroll
        for (int tb = 0; tb < 4; tb++) sa[tb] = zf;
#pragma unroll
        for (int kc = 0; kc < 4; kc++)
#pragma unroll
            for (int tb = 0; tb < 4; tb++) {
                bfrag bk = *(const bfrag*)&sm[KSb + SWZ((16 * tb + l16) * 128 + kc * 32 + quad * 8, l16)];
                sa[tb] = MFMA16(qf[kc], bk, sa[tb]);
            }

        // ---- softmax numerator; l accumulated per-lane ----
#pragma unroll
        for (int r = 0; r < 4; r++) {
            float p0 = __builtin_amdgcn_exp2f(sa[0][r]);
            float p1 = __builtin_amdgcn_exp2f(sa[1][r]);
            float p2 = __builtin_amdgcn_exp2f(sa[2][r]);
            float p3 = __builtin_amdgcn_exp2f(sa[3][r]);
            l_r[r] += (p0 + p1) + (p2 + p3);
            int row = 16 * wv + quad * 4 + r;
            int rb = row * 64 + l16;
            sm[PSb + SWZ(rb +  0, row)] = f2b(p0);
            sm[PSb + SWZ(rb + 16, row)] = f2b(p1);
            sm[PSb + SWZ(rb + 32, row)] = f2b(p2);
            sm[PSb + SWZ(rb + 48, row)] = f2b(p3);
        }
        // PS rows are wave-private: in-wave LDS ordering, no barrier needed.

        // ---- PV: O += P * G ----
#pragma unroll
        for (int tc = 0; tc < 2; tc++) {
            bfrag ap = *(const bfrag*)&sm[PSb + SWZ((16 * wv + l16) * 64 + tc * 32 + quad * 8, l16)];
#pragma unroll
            for (int kb = 0; kb < 8; kb++) {
                bfrag bg = *(const bfrag*)&sm[GTb + SWZ((16 * kb + l16) * 64 + tc * 32 + quad * 8, l16)];
                O[kb] = MFMA16(ap, bg, O[kb]);
            }
        }
    }

    __syncthreads();    // all waves' PV reads of KS/GT done before YS/WO reuse

    // ---------------- Phase 2: reduce l; y -> YS; out = x + Wo*y + bo ----
    {
        float rs0 = l_r[0], rs1 = l_r[1], rs2 = l_r[2], rs3 = l_r[3];
#pragma unroll
        for (int m = 1; m <= 8; m <<= 1) {
            rs0 += __shfl_xor(rs0, m);
            rs1 += __shfl_xor(rs1, m);
            rs2 += __shfl_xor(rs2, m);
            rs3 += __shfl_xor(rs3, m);
        }
        float lr0 = 1.0f / rs0, lr1 = 1.0f / rs1, lr2 = 1.0f / rs2, lr3 = 1.0f / rs3;
#pragma unroll
        for (int kb = 0; kb < 8; kb++) {
            int rowb = 16 * wv + quad * 4;
            sm[SWZ((rowb + 0) * 128 + l16 + 16 * kb, rowb + 0)] = f2b(O[kb][0] * lr0);
            sm[SWZ((rowb + 1) * 128 + l16 + 16 * kb, rowb + 1)] = f2b(O[kb][1] * lr1);
            sm[SWZ((rowb + 2) * 128 + l16 + 16 * kb, rowb + 2)] = f2b(O[kb][2] * lr2);
            sm[SWZ((rowb + 3) * 128 + l16 + 16 * kb, rowb + 3)] = f2b(O[kb][3] * lr3);
        }
    }

#pragma unroll
    for (int qtr = 0; qtr < 4; qtr++) {
        __syncthreads();    // GT (or prev WO) reads done before overwrite
        // stage Wo rows [qtr*64, qtr*64+64) bf16, swizzled [64][128]
#pragma unroll
        for (int i = 0; i < 8; i++) {
            int f = tid + i * 256;
            int c = f >> 5, ko = (f & 31) * 4;
            float4 w = *(const float4*)&Wo[(size_t)(qtr * 64 + c) * KCH + ko];
            ushort4 w4 = {f2b(w.x), f2b(w.y), f2b(w.z), f2b(w.w)};
            *(ushort4*)&sm[WOb + SWZ(c * 128 + ko, c)] = w4;
        }
        __syncthreads();

        ffrag zc[4];
#pragma unroll
        for (int cb = 0; cb < 4; cb++) zc[cb] = zf;
#pragma unroll
        for (int kc = 0; kc < 4; kc++) {
            bfrag ay = *(const bfrag*)&sm[SWZ((16 * wv + l16) * 128 + kc * 32 + quad * 8, l16)];
#pragma unroll
            for (int cb = 0; cb < 4; cb++) {
                bfrag bw = *(const bfrag*)&sm[WOb + SWZ((16 * cb + l16) * 128 + kc * 32 + quad * 8, l16)];
                zc[cb] = MFMA16(ay, bw, zc[cb]);
            }
        }
#pragma unroll
        for (int cb = 0; cb < 4; cb++) {
            int c = qtr * 64 + 16 * cb + l16;
            float bc = bo[c];
            size_t base = ((size_t)n * CCH + c) * SSP + q0 + 16 * wv + quad * 4;
            float4 xv = *(const float4*)&x[base];
            float4 ov;
            ov.x = xv.x + zc[cb][0] + bc;
            ov.y = xv.y + zc[cb][1] + bc;
            ov.z = xv.z + zc[cb][2] + bc;
            ov.w = xv.w + zc[cb][3] + bc;
            *(float4*)&out[base] = ov;
        }
    }
}

// ---------------------------------------------------------------------------
extern "C" void kernel_launch(void* const* d_in, const int* in_sizes, int n_in,
                              void* d_out, int out_size, void* d_ws, size_t ws_size,
                              hipStream_t stream) {
    const float* x  = (const float*)d_in[0];
    const float* Wg = (const float*)d_in[1];
    const float* bg = (const float*)d_in[2];
    const float* Wt = (const float*)d_in[3];
    const float* bt = (const float*)d_in[4];
    const float* Wp = (const float*)d_in[5];
    const float* bp = (const float*)d_in[6];
    const float* Wo = (const float*)d_in[7];
    const float* bo = (const float*)d_in[8];
    float* out = (float*)d_out;

    // ws: 16 MB total (verified-safe): G^T bf16 8MB + P bf16 8MB.
    u16* G = (u16*)d_ws;                       // [N,K,S] transposed
    u16* P = G + (size_t)NB * SSP * KCH;       // [N,S,K]

    proj_gp_kernel<<<dim3(NB * SSP / 64), 256, 0, stream>>>(x, Wg, bg, Wp, bp, G, P);
    attn_fused_kernel<<<dim3(NB * SSP / 64), 256, 0, stream>>>(x, Wt, bt, P, G, Wo, bo, out);
}

// Round 7
// 426.665 us; speedup vs baseline: 1.7260x; 1.7260x over previous
//
#include <hip/hip_runtime.h>
#include <hip/hip_bf16.h>

#define NB   8
#define CCH  256
#define KCH  128
#define SSP  4096

typedef unsigned short u16;
typedef __attribute__((ext_vector_type(8))) short  bfrag;  // 8 bf16 = 4 VGPRs
typedef __attribute__((ext_vector_type(4))) float  ffrag;  // 4 fp32 acc

#define MFMA16(a, b, c) __builtin_amdgcn_mfma_f32_16x16x32_bf16((a), (b), (c), 0, 0, 0)
// u16-index XOR swizzle: flips bits 3-5 (16B granule) by row&7 -> bank spread
#define SWZ(i, r) ((unsigned)(i) ^ ((((unsigned)(r)) & 7u) << 3))

__device__ __forceinline__ u16 f2b(float f) {            // fp32 -> bf16 RNE
    union { float f; unsigned u; } v; v.f = f;
    return (u16)((v.u + 0x7fffu + ((v.u >> 16) & 1u)) >> 16);
}

// ---------------------------------------------------------------------------
// K1: g and phi projections, MFMA, register-pipelined staging. (unchanged)
// ---------------------------------------------------------------------------
__global__ __launch_bounds__(256, 2) void proj_gp_kernel(
    const float* __restrict__ x,
    const float* __restrict__ Wg, const float* __restrict__ bg,
    const float* __restrict__ Wp, const float* __restrict__ bp,
    u16* __restrict__ G,   // [N,K,S] transposed
    u16* __restrict__ P)   // [N,S,K]
{
    __shared__ __align__(16) u16 sm[12800];
    const int tid  = threadIdx.x;
    const int wv   = tid >> 6;
    const int lane = tid & 63;
    const int quad = lane >> 4, l16 = lane & 15;
    const int bid  = blockIdx.x;
    const int n  = bid & 7;
    const int s0 = (bid >> 3) * 64;

    const ffrag zf = {0.f, 0.f, 0.f, 0.f};
    ffrag ga[8], pa[8];
#pragma unroll
    for (int kb = 0; kb < 8; kb++) { ga[kb] = zf; pa[kb] = zf; }

    float4 xreg[2], wgreg[4], wpreg[4];
#pragma unroll
    for (int i = 0; i < 2; i++) {
        int f = tid + i * 256;
        int c = f >> 4, s4 = (f & 15) * 4;
        xreg[i] = *(const float4*)&x[((size_t)n * CCH + c) * SSP + s0 + s4];
    }
#pragma unroll
    for (int i = 0; i < 4; i++) {
        int f = tid + i * 256;
        int k = f >> 3, co = (f & 7) * 4;
        wgreg[i] = *(const float4*)&Wg[k * CCH + co];
        wpreg[i] = *(const float4*)&Wp[k * CCH + co];
    }

    for (int c0 = 0; c0 < CCH; c0 += 32) {
        __syncthreads();
#pragma unroll
        for (int i = 0; i < 2; i++) {
            int f = tid + i * 256;
            int c = f >> 4, s4 = (f & 15) * 4;
            sm[(s4 + 0) * 40 + c] = f2b(xreg[i].x);
            sm[(s4 + 1) * 40 + c] = f2b(xreg[i].y);
            sm[(s4 + 2) * 40 + c] = f2b(xreg[i].z);
            sm[(s4 + 3) * 40 + c] = f2b(xreg[i].w);
        }
#pragma unroll
        for (int i = 0; i < 4; i++) {
            int f = tid + i * 256;
            int k = f >> 3, co = (f & 7) * 4;
            ushort4 g4 = {f2b(wgreg[i].x), f2b(wgreg[i].y), f2b(wgreg[i].z), f2b(wgreg[i].w)};
            ushort4 p4 = {f2b(wpreg[i].x), f2b(wpreg[i].y), f2b(wpreg[i].z), f2b(wpreg[i].w)};
            *(ushort4*)&sm[2560 + k * 40 + co] = g4;
            *(ushort4*)&sm[7680 + k * 40 + co] = p4;
        }
        if (c0 + 32 < CCH) {
#pragma unroll
            for (int i = 0; i < 2; i++) {
                int f = tid + i * 256;
                int c = f >> 4, s4 = (f & 15) * 4;
                xreg[i] = *(const float4*)&x[((size_t)n * CCH + c0 + 32 + c) * SSP + s0 + s4];
            }
#pragma unroll
            for (int i = 0; i < 4; i++) {
                int f = tid + i * 256;
                int k = f >> 3, co = (f & 7) * 4;
                wgreg[i] = *(const float4*)&Wg[k * CCH + c0 + 32 + co];
                wpreg[i] = *(const float4*)&Wp[k * CCH + c0 + 32 + co];
            }
        }
        __syncthreads();
        bfrag a = *(const bfrag*)&sm[(16 * wv + l16) * 40 + quad * 8];
#pragma unroll
        for (int kb = 0; kb < 8; kb++) {
            bfrag bgf = *(const bfrag*)&sm[2560 + (16 * kb + l16) * 40 + quad * 8];
            bfrag bpf = *(const bfrag*)&sm[7680 + (16 * kb + l16) * 40 + quad * 8];
            ga[kb] = MFMA16(a, bgf, ga[kb]);
            pa[kb] = MFMA16(a, bpf, pa[kb]);
        }
    }
#pragma unroll
    for (int kb = 0; kb < 8; kb++) {
        int k = l16 + 16 * kb;
        float bgv = bg[k], bpv = bp[k];
        int srow = s0 + 16 * wv + quad * 4;
        ushort4 g4 = {f2b(ga[kb][0] + bgv), f2b(ga[kb][1] + bgv),
                      f2b(ga[kb][2] + bgv), f2b(ga[kb][3] + bgv)};
        *(ushort4*)&G[(size_t)n * KCH * SSP + (size_t)k * SSP + srow] = g4;
#pragma unroll
        for (int r = 0; r < 4; r++)
            P[((size_t)n * SSP + srow + r) * KCH + k] = f2b(pa[kb][r] + bpv);
    }
}

// ---------------------------------------------------------------------------
// K2: fused theta-proj + flash attention + out-proj, all MFMA.
// Round-12 vs round 6: t-loop re-synchronized (T3/T4-minimal, reg-staged).
// Diagnosis: every prior round was grid-capped at 8 waves/CU AND paid a full
// vmcnt(0)+lgkmcnt(0) drain at BOTH __syncthreads per iteration (the HIP
// compiler emits the full drain before s_barrier), so the "prefetch" never
// survived a barrier and all waves idled together each tile.
// Changes:
//  - KS/GT double-buffered (2x16KB each). Iter i: commit tile i+1 to the
//    idle buffer IN PARALLEL with computing tile i from the live buffer;
//    issue tile i+2 global loads mid-iter (they stay in flight across the
//    barrier - counted vmcnt at the next commit, never a forced drain).
//  - ONE raw barrier per iter: s_waitcnt lgkmcnt(0); s_barrier. No vmcnt.
//  - __launch_bounds__(256,2): no artificial VGPR cap (round-6 spill gone).
// LDS map (u16 idx, 36864 = 72 KB, 2 blocks/CU):
//   KS0@0  KS1@8192  GT0@16384  GT1@24576  PS@32768..36863
//   aliases: QS/YS@8192(KS1: QS consumed pre-loop, YS post-loop);
//            XT@16384+WT@18944 (GT0, phase 0 only); WO@24576 (GT1, epilogue).
// ---------------------------------------------------------------------------
__global__ __launch_bounds__(256, 2) void attn_fused_kernel(
    const float* __restrict__ x,
    const float* __restrict__ Wt, const float* __restrict__ bt,
    const u16* __restrict__ Pb,   // phi rows bf16 [N,S,K]
    const u16* __restrict__ Gt,   // g bf16 TRANSPOSED [N,K,S]
    const float* __restrict__ Wo, const float* __restrict__ bo,
    float* __restrict__ out)
{
    __shared__ __align__(16) u16 sm[36864];     // 72 KB
    const int tid  = threadIdx.x;
    const int wv   = tid >> 6;                  // 0..3
    const int lane = tid & 63;
    const int quad = lane >> 4, l16 = lane & 15;
    const int bid  = blockIdx.x;
    const int n    = bid & 7;
    const int q0   = (bid >> 3) * 64;
    // 1/sqrt(128) * log2(e): exp(s*scale) == exp2(s*qscale)
    const float qscale = 0.08838834764831845f * 1.4426950408889634f;
    const ffrag zf = {0.f, 0.f, 0.f, 0.f};

    const int KS0b = 0, KS1b = 8192, GT0b = 16384, GT1b = 24576, PSb = 32768;
    const int QSb = 8192, XTb = 16384, WTb = 18944, WOb = 24576;

    const u16* Pbase = Pb + (size_t)n * SSP * KCH;
    const u16* Gbase = Gt + (size_t)n * KCH * SSP;

    // ---- issue tile-0 loads NOW; they complete during phase 0 ----
    uint4 kreg[4], greg[4];
#pragma unroll
    for (int i = 0; i < 4; i++) {
        int f = tid + i * 256;
        int row = f >> 4, c8 = (f & 15) * 8;
        kreg[i] = *(const uint4*)(Pbase + (size_t)row * KCH + c8);
    }
#pragma unroll
    for (int i = 0; i < 4; i++) {
        int f = tid + i * 256;
        int k = f >> 3, ch = f & 7;
        greg[i] = *(const uint4*)(Gbase + (size_t)k * SSP + ch * 8);
    }

    // ---------------- Phase 0: Qs = (theta(x)+bt)*qscale, bf16 ----------------
    {
        ffrag qa[8];
#pragma unroll
        for (int kb = 0; kb < 8; kb++) qa[kb] = zf;

        for (int c0 = 0; c0 < CCH; c0 += 32) {
#pragma unroll
            for (int i = 0; i < 2; i++) {
                int f = tid + i * 256;
                int c = f >> 4, s4 = (f & 15) * 4;
                float4 xv = *(const float4*)&x[((size_t)n * CCH + c0 + c) * SSP + q0 + s4];
                sm[XTb + (s4 + 0) * 40 + c] = f2b(xv.x);
                sm[XTb + (s4 + 1) * 40 + c] = f2b(xv.y);
                sm[XTb + (s4 + 2) * 40 + c] = f2b(xv.z);
                sm[XTb + (s4 + 3) * 40 + c] = f2b(xv.w);
            }
#pragma unroll
            for (int i = 0; i < 4; i++) {
                int f = tid + i * 256;
                int k = f >> 3, co = (f & 7) * 4;
                float4 wq4 = *(const float4*)&Wt[k * CCH + c0 + co];
                ushort4 q4 = {f2b(wq4.x), f2b(wq4.y), f2b(wq4.z), f2b(wq4.w)};
                *(ushort4*)&sm[WTb + k * 40 + co] = q4;
            }
            __syncthreads();
            bfrag aq = *(const bfrag*)&sm[XTb + (16 * wv + l16) * 40 + quad * 8];
#pragma unroll
            for (int kb = 0; kb < 8; kb++) {
                bfrag bw = *(const bfrag*)&sm[WTb + (16 * kb + l16) * 40 + quad * 8];
                qa[kb] = MFMA16(aq, bw, qa[kb]);
            }
            __syncthreads();
        }
#pragma unroll
        for (int kb = 0; kb < 8; kb++) {
            float btv = bt[l16 + 16 * kb];
#pragma unroll
            for (int r = 0; r < 4; r++) {
                int row = 16 * wv + quad * 4 + r;
                sm[QSb + SWZ(row * 128 + l16 + 16 * kb, row)] = f2b((qa[kb][r] + btv) * qscale);
            }
        }
        // QS rows are wave-private; in-wave LDS ordering suffices below.
    }

    // ---- hoist Q A-fragments (own rows, no barrier needed) ----
    bfrag qf[4];
#pragma unroll
    for (int kc = 0; kc < 4; kc++)
        qf[kc] = *(const bfrag*)&sm[QSb + SWZ((16 * wv + l16) * 128 + kc * 32 + quad * 8, l16)];

    // ---- prologue: commit tile 0 -> buf0, issue tile-1 loads, barrier ----
#pragma unroll
    for (int i = 0; i < 4; i++) {
        int f = tid + i * 256;
        int row = f >> 4, c8 = (f & 15) * 8;
        *(uint4*)&sm[KS0b + SWZ(row * 128 + c8, row)] = kreg[i];
    }
#pragma unroll
    for (int i = 0; i < 4; i++) {
        int f = tid + i * 256;
        int k = f >> 3, ch = f & 7;
        *(uint4*)&sm[GT0b + SWZ(k * 64 + ch * 8, k)] = greg[i];
    }
#pragma unroll
    for (int i = 0; i < 4; i++) {
        int f = tid + i * 256;
        int row = f >> 4, c8 = (f & 15) * 8;
        kreg[i] = *(const uint4*)(Pbase + (size_t)(64 + row) * KCH + c8);
    }
#pragma unroll
    for (int i = 0; i < 4; i++) {
        int f = tid + i * 256;
        int k = f >> 3, ch = f & 7;
        greg[i] = *(const uint4*)(Gbase + (size_t)k * SSP + 64 + ch * 8);
    }
    asm volatile("s_waitcnt lgkmcnt(0)" ::: "memory");
    __builtin_amdgcn_s_barrier();

    // ---------------- Phase 1: flash attention over t-tiles ----------------
    ffrag O[8];
#pragma unroll
    for (int kb = 0; kb < 8; kb++) O[kb] = zf;
    float l_r[4] = {0.f, 0.f, 0.f, 0.f};

    const int NT = SSP / 64;        // 64 tiles
#pragma unroll 2
    for (int it = 0; it < NT; ++it) {
        const int cur = it & 1;
        const int KS  = cur ? KS1b : KS0b;
        const int GT  = cur ? GT1b : GT0b;

        // ---- commit tile it+1 to the idle buffer (overlaps compute) ----
        if (it + 1 < NT) {
            const int KSw = cur ? KS0b : KS1b;
            const int GTw = cur ? GT0b : GT1b;
#pragma unroll
            for (int i = 0; i < 4; i++) {
                int f = tid + i * 256;
                int row = f >> 4, c8 = (f & 15) * 8;
                *(uint4*)&sm[KSw + SWZ(row * 128 + c8, row)] = kreg[i];
            }
#pragma unroll
            for (int i = 0; i < 4; i++) {
                int f = tid + i * 256;
                int k = f >> 3, ch = f & 7;
                *(uint4*)&sm[GTw + SWZ(k * 64 + ch * 8, k)] = greg[i];
            }
            // ---- issue tile it+2 loads; they cross the barrier in flight ----
            if (it + 2 < NT) {
                int tb = (it + 2) * 64;
#pragma unroll
                for (int i = 0; i < 4; i++) {
                    int f = tid + i * 256;
                    int row = f >> 4, c8 = (f & 15) * 8;
                    kreg[i] = *(const uint4*)(Pbase + (size_t)(tb + row) * KCH + c8);
                }
#pragma unroll
                for (int i = 0; i < 4; i++) {
                    int f = tid + i * 256;
                    int k = f >> 3, ch = f & 7;
                    greg[i] = *(const uint4*)(Gbase + (size_t)k * SSP + tb + ch * 8);
                }
            }
        }

        // ---- QK^T (Q from registers) ----
        ffrag sa[4];
#pragma unroll
        for (int tb = 0; tb < 4; tb++) sa[tb] = zf;
#pragma unroll
        for (int kc = 0; kc < 4; kc++)
#pragma unroll
            for (int tb = 0; tb < 4; tb++) {
                bfrag bk = *(const bfrag*)&sm[KS + SWZ((16 * tb + l16) * 128 + kc * 32 + quad * 8, l16)];
                sa[tb] = MFMA16(qf[kc], bk, sa[tb]);
            }

        // ---- softmax numerator; l accumulated per-lane ----
#pragma unroll
        for (int r = 0; r < 4; r++) {
            float p0 = __builtin_amdgcn_exp2f(sa[0][r]);
            float p1 = __builtin_amdgcn_exp2f(sa[1][r]);
            float p2 = __builtin_amdgcn_exp2f(sa[2][r]);
            float p3 = __builtin_amdgcn_exp2f(sa[3][r]);
            l_r[r] += (p0 + p1) + (p2 + p3);
            int row = 16 * wv + quad * 4 + r;
            int rb = row * 64 + l16;
            sm[PSb + SWZ(rb +  0, row)] = f2b(p0);
            sm[PSb + SWZ(rb + 16, row)] = f2b(p1);
            sm[PSb + SWZ(rb + 32, row)] = f2b(p2);
            sm[PSb + SWZ(rb + 48, row)] = f2b(p3);
        }
        // PS rows are wave-private: in-wave LDS ordering, no barrier needed.

        // ---- PV: O += P * G ----
#pragma unroll
        for (int tc = 0; tc < 2; tc++) {
            bfrag ap = *(const bfrag*)&sm[PSb + SWZ((16 * wv + l16) * 64 + tc * 32 + quad * 8, l16)];
#pragma unroll
            for (int kb = 0; kb < 8; kb++) {
                bfrag bg = *(const bfrag*)&sm[GT + SWZ((16 * kb + l16) * 64 + tc * 32 + quad * 8, l16)];
                O[kb] = MFMA16(ap, bg, O[kb]);
            }
        }

        // ---- ONE barrier per iter; ds ops drained, vmcnt stays in flight ----
        asm volatile("s_waitcnt lgkmcnt(0)" ::: "memory");
        __builtin_amdgcn_s_barrier();
    }

    // ---------------- Phase 2: reduce l; y -> YS; out = x + Wo*y + bo ----
    {
        float rs0 = l_r[0], rs1 = l_r[1], rs2 = l_r[2], rs3 = l_r[3];
#pragma unroll
        for (int m = 1; m <= 8; m <<= 1) {
            rs0 += __shfl_xor(rs0, m);
            rs1 += __shfl_xor(rs1, m);
            rs2 += __shfl_xor(rs2, m);
            rs3 += __shfl_xor(rs3, m);
        }
        float lr0 = 1.0f / rs0, lr1 = 1.0f / rs1, lr2 = 1.0f / rs2, lr3 = 1.0f / rs3;
#pragma unroll
        for (int kb = 0; kb < 8; kb++) {
            int rowb = 16 * wv + quad * 4;
            sm[QSb + SWZ((rowb + 0) * 128 + l16 + 16 * kb, rowb + 0)] = f2b(O[kb][0] * lr0);
            sm[QSb + SWZ((rowb + 1) * 128 + l16 + 16 * kb, rowb + 1)] = f2b(O[kb][1] * lr1);
            sm[QSb + SWZ((rowb + 2) * 128 + l16 + 16 * kb, rowb + 2)] = f2b(O[kb][2] * lr2);
            sm[QSb + SWZ((rowb + 3) * 128 + l16 + 16 * kb, rowb + 3)] = f2b(O[kb][3] * lr3);
        }
    }

#pragma unroll
    for (int qtr = 0; qtr < 4; qtr++) {
        __syncthreads();    // last-iter GT1 reads / prev WO reads done
        // stage Wo rows [qtr*64, qtr*64+64) bf16, swizzled [64][128]
#pragma unroll
        for (int i = 0; i < 8; i++) {
            int f = tid + i * 256;
            int c = f >> 5, ko = (f & 31) * 4;
            float4 w = *(const float4*)&Wo[(size_t)(qtr * 64 + c) * KCH + ko];
            ushort4 w4 = {f2b(w.x), f2b(w.y), f2b(w.z), f2b(w.w)};
            *(ushort4*)&sm[WOb + SWZ(c * 128 + ko, c)] = w4;
        }
        __syncthreads();

        ffrag zc[4];
#pragma unroll
        for (int cb = 0; cb < 4; cb++) zc[cb] = zf;
#pragma unroll
        for (int kc = 0; kc < 4; kc++) {
            bfrag ay = *(const bfrag*)&sm[QSb + SWZ((16 * wv + l16) * 128 + kc * 32 + quad * 8, l16)];
#pragma unroll
            for (int cb = 0; cb < 4; cb++) {
                bfrag bw = *(const bfrag*)&sm[WOb + SWZ((16 * cb + l16) * 128 + kc * 32 + quad * 8, l16)];
                zc[cb] = MFMA16(ay, bw, zc[cb]);
            }
        }
#pragma unroll
        for (int cb = 0; cb < 4; cb++) {
            int c = qtr * 64 + 16 * cb + l16;
            float bc = bo[c];
            size_t base = ((size_t)n * CCH + c) * SSP + q0 + 16 * wv + quad * 4;
            float4 xv = *(const float4*)&x[base];
            float4 ov;
            ov.x = xv.x + zc[cb][0] + bc;
            ov.y = xv.y + zc[cb][1] + bc;
            ov.z = xv.z + zc[cb][2] + bc;
            ov.w = xv.w + zc[cb][3] + bc;
            *(float4*)&out[base] = ov;
        }
    }
}

// ---------------------------------------------------------------------------
extern "C" void kernel_launch(void* const* d_in, const int* in_sizes, int n_in,
                              void* d_out, int out_size, void* d_ws, size_t ws_size,
                              hipStream_t stream) {
    const float* x  = (const float*)d_in[0];
    const float* Wg = (const float*)d_in[1];
    const float* bg = (const float*)d_in[2];
    const float* Wt = (const float*)d_in[3];
    const float* bt = (const float*)d_in[4];
    const float* Wp = (const float*)d_in[5];
    const float* bp = (const float*)d_in[6];
    const float* Wo = (const float*)d_in[7];
    const float* bo = (const float*)d_in[8];
    float* out = (float*)d_out;

    // ws: 16 MB total (verified-safe): G^T bf16 8MB + P bf16 8MB.
    u16* G = (u16*)d_ws;                       // [N,K,S] transposed
    u16* P = G + (size_t)NB * SSP * KCH;       // [N,S,K]

    proj_gp_kernel<<<dim3(NB * SSP / 64), 256, 0, stream>>>(x, Wg, bg, Wp, bp, G, P);
    attn_fused_kernel<<<dim3(NB * SSP / 64), 256, 0, stream>>>(x, Wt, bt, P, G, Wo, bo, out);
}

// Round 8
// 217.622 us; speedup vs baseline: 3.3840x; 1.9606x over previous
//
#include <hip/hip_runtime.h>
#include <hip/hip_bf16.h>

#define NB   8
#define CCH  256
#define KCH  128
#define SSP  4096

typedef unsigned short u16;
typedef __attribute__((ext_vector_type(8))) short  bfrag;  // 8 bf16 = 4 VGPRs
typedef __attribute__((ext_vector_type(4))) float  ffrag;  // 4 fp32 acc

#define MFMA16(a, b, c) __builtin_amdgcn_mfma_f32_16x16x32_bf16((a), (b), (c), 0, 0, 0)
// u16-index XOR swizzle: flips bits 3-5 (16B granule) by row&7 -> bank spread
#define SWZ(i, r) ((unsigned)(i) ^ ((((unsigned)(r)) & 7u) << 3))

// global -> LDS direct DMA, 16B per lane. LDS dest is WAVE-UNIFORM base
// (+lane*16 by HW); global src is PER-LANE (pre-swizzled => rule #21 combo:
// linear LDS dest + inverse-swizzled source + swizzled read).
#define GLDS(G, L) __builtin_amdgcn_global_load_lds(                          \
    (const __attribute__((address_space(1))) void*)(G),                       \
    (__attribute__((address_space(3))) void*)(L), 16, 0, 0)

__device__ __forceinline__ u16 f2b(float f) {            // fp32 -> bf16 RNE
    union { float f; unsigned u; } v; v.f = f;
    return (u16)((v.u + 0x7fffu + ((v.u >> 16) & 1u)) >> 16);
}

// ---------------------------------------------------------------------------
// K1: g and phi projections, MFMA, register-pipelined staging. (unchanged)
// ---------------------------------------------------------------------------
__global__ __launch_bounds__(256, 2) void proj_gp_kernel(
    const float* __restrict__ x,
    const float* __restrict__ Wg, const float* __restrict__ bg,
    const float* __restrict__ Wp, const float* __restrict__ bp,
    u16* __restrict__ G,   // [N,K,S] transposed
    u16* __restrict__ P)   // [N,S,K]
{
    __shared__ __align__(16) u16 sm[12800];
    const int tid  = threadIdx.x;
    const int wv   = tid >> 6;
    const int lane = tid & 63;
    const int quad = lane >> 4, l16 = lane & 15;
    const int bid  = blockIdx.x;
    const int n  = bid & 7;
    const int s0 = (bid >> 3) * 64;

    const ffrag zf = {0.f, 0.f, 0.f, 0.f};
    ffrag ga[8], pa[8];
#pragma unroll
    for (int kb = 0; kb < 8; kb++) { ga[kb] = zf; pa[kb] = zf; }

    float4 xreg[2], wgreg[4], wpreg[4];
#pragma unroll
    for (int i = 0; i < 2; i++) {
        int f = tid + i * 256;
        int c = f >> 4, s4 = (f & 15) * 4;
        xreg[i] = *(const float4*)&x[((size_t)n * CCH + c) * SSP + s0 + s4];
    }
#pragma unroll
    for (int i = 0; i < 4; i++) {
        int f = tid + i * 256;
        int k = f >> 3, co = (f & 7) * 4;
        wgreg[i] = *(const float4*)&Wg[k * CCH + co];
        wpreg[i] = *(const float4*)&Wp[k * CCH + co];
    }

    for (int c0 = 0; c0 < CCH; c0 += 32) {
        __syncthreads();
#pragma unroll
        for (int i = 0; i < 2; i++) {
            int f = tid + i * 256;
            int c = f >> 4, s4 = (f & 15) * 4;
            sm[(s4 + 0) * 40 + c] = f2b(xreg[i].x);
            sm[(s4 + 1) * 40 + c] = f2b(xreg[i].y);
            sm[(s4 + 2) * 40 + c] = f2b(xreg[i].z);
            sm[(s4 + 3) * 40 + c] = f2b(xreg[i].w);
        }
#pragma unroll
        for (int i = 0; i < 4; i++) {
            int f = tid + i * 256;
            int k = f >> 3, co = (f & 7) * 4;
            ushort4 g4 = {f2b(wgreg[i].x), f2b(wgreg[i].y), f2b(wgreg[i].z), f2b(wgreg[i].w)};
            ushort4 p4 = {f2b(wpreg[i].x), f2b(wpreg[i].y), f2b(wpreg[i].z), f2b(wpreg[i].w)};
            *(ushort4*)&sm[2560 + k * 40 + co] = g4;
            *(ushort4*)&sm[7680 + k * 40 + co] = p4;
        }
        if (c0 + 32 < CCH) {
#pragma unroll
            for (int i = 0; i < 2; i++) {
                int f = tid + i * 256;
                int c = f >> 4, s4 = (f & 15) * 4;
                xreg[i] = *(const float4*)&x[((size_t)n * CCH + c0 + 32 + c) * SSP + s0 + s4];
            }
#pragma unroll
            for (int i = 0; i < 4; i++) {
                int f = tid + i * 256;
                int k = f >> 3, co = (f & 7) * 4;
                wgreg[i] = *(const float4*)&Wg[k * CCH + c0 + 32 + co];
                wpreg[i] = *(const float4*)&Wp[k * CCH + c0 + 32 + co];
            }
        }
        __syncthreads();
        bfrag a = *(const bfrag*)&sm[(16 * wv + l16) * 40 + quad * 8];
#pragma unroll
        for (int kb = 0; kb < 8; kb++) {
            bfrag bgf = *(const bfrag*)&sm[2560 + (16 * kb + l16) * 40 + quad * 8];
            bfrag bpf = *(const bfrag*)&sm[7680 + (16 * kb + l16) * 40 + quad * 8];
            ga[kb] = MFMA16(a, bgf, ga[kb]);
            pa[kb] = MFMA16(a, bpf, pa[kb]);
        }
    }
#pragma unroll
    for (int kb = 0; kb < 8; kb++) {
        int k = l16 + 16 * kb;
        float bgv = bg[k], bpv = bp[k];
        int srow = s0 + 16 * wv + quad * 4;
        ushort4 g4 = {f2b(ga[kb][0] + bgv), f2b(ga[kb][1] + bgv),
                      f2b(ga[kb][2] + bgv), f2b(ga[kb][3] + bgv)};
        *(ushort4*)&G[(size_t)n * KCH * SSP + (size_t)k * SSP + srow] = g4;
#pragma unroll
        for (int r = 0; r < 4; r++)
            P[((size_t)n * SSP + srow + r) * KCH + k] = f2b(pa[kb][r] + bpv);
    }
}

// ---------------------------------------------------------------------------
// K2: fused theta-proj + flash attention + out-proj, all MFMA.
// Round-13 vs round 7: staging via __builtin_amdgcn_global_load_lds.
// Diagnosis chain: rounds 3-7 all had a compiler scratch stream (WRITE_SIZE
// 266-490 MB) tied to register-staging aggregates held across the loop;
// unreachable by source rewrites. gload_lds removes the register stage
// entirely (nothing left to scratch) AND gives true issue-early/drain-late:
// the 8 DMA loads for tile i+1 are issued BEFORE compute of tile i and
// drained by ONE vmcnt(0) AFTER compute (latency hidden; rounds 0-2 drained
// immediately after issue at the second __syncthreads).
// Swizzle per rule #21: LDS dest linear, global SOURCE pre-swizzled with the
// same XOR involution (col ^= (row&7)<<3 in u16), read side unchanged.
// LDS map (u16 idx, 36864 = 72 KB, 2 blocks/CU):
//   KS0@0  KS1@8192  GT0@16384  GT1@24576  PS@32768
//   aliases in KS1: XT@8192+WT@10752 (phase 0), QS@8192 (pre-loop), YS (epi)
//   alias  in GT1: WO@24576 (epilogue).  buf0 is never aliased.
// ---------------------------------------------------------------------------
__global__ __launch_bounds__(256, 2) void attn_fused_kernel(
    const float* __restrict__ x,
    const float* __restrict__ Wt, const float* __restrict__ bt,
    const u16* __restrict__ Pb,   // phi rows bf16 [N,S,K]
    const u16* __restrict__ Gt,   // g bf16 TRANSPOSED [N,K,S]
    const float* __restrict__ Wo, const float* __restrict__ bo,
    float* __restrict__ out)
{
    __shared__ __align__(16) u16 sm[36864];     // 72 KB
    const int tid  = threadIdx.x;
    const int wv   = tid >> 6;                  // 0..3
    const int lane = tid & 63;
    const int quad = lane >> 4, l16 = lane & 15;
    const int bid  = blockIdx.x;
    const int n    = bid & 7;
    const int q0   = (bid >> 3) * 64;
    // 1/sqrt(128) * log2(e): exp(s*scale) == exp2(s*qscale)
    const float qscale = 0.08838834764831845f * 1.4426950408889634f;
    const ffrag zf = {0.f, 0.f, 0.f, 0.f};

    const int KS0b = 0, KS1b = 8192, GT0b = 16384, GT1b = 24576, PSb = 32768;
    const int XTb = 8192, WTb = 10752, QSb = 8192, WOb = 24576;

    const u16* Pbase = Pb + (size_t)n * SSP * KCH;
    const u16* Gbase = Gt + (size_t)n * KCH * SSP;

// Stage one K-tile [64 t][128 k] + one G-tile [128 k][64 t] (16 KB each)
// into KSw/GTw for t-base T0. 8 gload_lds per wave; LDS dest wave-uniform,
// global source pre-swizzled per-lane.
#define STAGE_TILE(KSw, GTw, T0)                                             \
    {                                                                        \
        _Pragma("unroll")                                                    \
        for (int i = 0; i < 4; i++) {                                        \
            int chunk = wv * 4 + i;                                          \
            int row = chunk * 4 + (lane >> 4);                               \
            int cs  = ((lane & 15) * 8) ^ ((row & 7) << 3);                  \
            GLDS(Pbase + (size_t)((T0) + row) * KCH + cs,                    \
                 &sm[(KSw) + chunk * 512]);                                  \
        }                                                                    \
        _Pragma("unroll")                                                    \
        for (int i = 0; i < 4; i++) {                                        \
            int chunk = wv * 4 + i;                                          \
            int k  = chunk * 8 + (lane >> 3);                                \
            int cs = ((lane & 7) * 8) ^ ((k & 7) << 3);                      \
            GLDS(Gbase + (size_t)k * SSP + (T0) + cs,                        \
                 &sm[(GTw) + chunk * 512]);                                  \
        }                                                                    \
    }

    // ---- tile 0 -> buf0 DMA issued NOW; flies under all of phase 0 ----
    STAGE_TILE(KS0b, GT0b, 0)

    // ---------------- Phase 0: Qs = (theta(x)+bt)*qscale, bf16 ----------------
    {
        ffrag qa[8];
#pragma unroll
        for (int kb = 0; kb < 8; kb++) qa[kb] = zf;

        for (int c0 = 0; c0 < CCH; c0 += 32) {
#pragma unroll
            for (int i = 0; i < 2; i++) {
                int f = tid + i * 256;
                int c = f >> 4, s4 = (f & 15) * 4;
                float4 xv = *(const float4*)&x[((size_t)n * CCH + c0 + c) * SSP + q0 + s4];
                sm[XTb + (s4 + 0) * 40 + c] = f2b(xv.x);
                sm[XTb + (s4 + 1) * 40 + c] = f2b(xv.y);
                sm[XTb + (s4 + 2) * 40 + c] = f2b(xv.z);
                sm[XTb + (s4 + 3) * 40 + c] = f2b(xv.w);
            }
#pragma unroll
            for (int i = 0; i < 4; i++) {
                int f = tid + i * 256;
                int k = f >> 3, co = (f & 7) * 4;
                float4 wq4 = *(const float4*)&Wt[k * CCH + c0 + co];
                ushort4 q4 = {f2b(wq4.x), f2b(wq4.y), f2b(wq4.z), f2b(wq4.w)};
                *(ushort4*)&sm[WTb + k * 40 + co] = q4;
            }
            __syncthreads();
            bfrag aq = *(const bfrag*)&sm[XTb + (16 * wv + l16) * 40 + quad * 8];
#pragma unroll
            for (int kb = 0; kb < 8; kb++) {
                bfrag bw = *(const bfrag*)&sm[WTb + (16 * kb + l16) * 40 + quad * 8];
                qa[kb] = MFMA16(aq, bw, qa[kb]);
            }
            __syncthreads();
        }
#pragma unroll
        for (int kb = 0; kb < 8; kb++) {
            float btv = bt[l16 + 16 * kb];
#pragma unroll
            for (int r = 0; r < 4; r++) {
                int row = 16 * wv + quad * 4 + r;
                sm[QSb + SWZ(row * 128 + l16 + 16 * kb, row)] = f2b((qa[kb][r] + btv) * qscale);
            }
        }
        // QS rows are wave-private; in-wave LDS ordering suffices below.
    }

    // ---- hoist Q A-fragments (own rows, no barrier needed) ----
    bfrag qf[4];
#pragma unroll
    for (int kc = 0; kc < 4; kc++)
        qf[kc] = *(const bfrag*)&sm[QSb + SWZ((16 * wv + l16) * 128 + kc * 32 + quad * 8, l16)];

    // ---- prologue sync: tile-0 DMA visible, QS reads retired ----
    asm volatile("s_waitcnt vmcnt(0) lgkmcnt(0)" ::: "memory");
    __builtin_amdgcn_s_barrier();

    // ---------------- Phase 1: flash attention over t-tiles ----------------
    ffrag O[8];
#pragma unroll
    for (int kb = 0; kb < 8; kb++) O[kb] = zf;
    float l_r[4] = {0.f, 0.f, 0.f, 0.f};

    const int NT = SSP / 64;        // 64 tiles
#pragma unroll 2
    for (int it = 0; it < NT; ++it) {
        const int cur = it & 1;
        const int KS  = cur ? KS1b : KS0b;
        const int GT  = cur ? GT1b : GT0b;

        // ---- issue tile it+1 DMA into the idle buffer (drains after compute) ----
        if (it + 1 < NT) {
            const int KSw = cur ? KS0b : KS1b;
            const int GTw = cur ? GT0b : GT1b;
            STAGE_TILE(KSw, GTw, (it + 1) * 64)
        }

        // ---- QK^T (Q from registers) ----
        ffrag sa[4];
#pragma unroll
        for (int tb = 0; tb < 4; tb++) sa[tb] = zf;
#pragma unroll
        for (int kc = 0; kc < 4; kc++)
#pragma unroll
            for (int tb = 0; tb < 4; tb++) {
                bfrag bk = *(const bfrag*)&sm[KS + SWZ((16 * tb + l16) * 128 + kc * 32 + quad * 8, l16)];
                sa[tb] = MFMA16(qf[kc], bk, sa[tb]);
            }

        // ---- softmax numerator; l accumulated per-lane ----
#pragma unroll
        for (int r = 0; r < 4; r++) {
            float p0 = __builtin_amdgcn_exp2f(sa[0][r]);
            float p1 = __builtin_amdgcn_exp2f(sa[1][r]);
            float p2 = __builtin_amdgcn_exp2f(sa[2][r]);
            float p3 = __builtin_amdgcn_exp2f(sa[3][r]);
            l_r[r] += (p0 + p1) + (p2 + p3);
            int row = 16 * wv + quad * 4 + r;
            int rb = row * 64 + l16;
            sm[PSb + SWZ(rb +  0, row)] = f2b(p0);
            sm[PSb + SWZ(rb + 16, row)] = f2b(p1);
            sm[PSb + SWZ(rb + 32, row)] = f2b(p2);
            sm[PSb + SWZ(rb + 48, row)] = f2b(p3);
        }
        // PS rows are wave-private: in-wave LDS ordering, no barrier needed.

        // ---- PV: O += P * G ----
#pragma unroll
        for (int tc = 0; tc < 2; tc++) {
            bfrag ap = *(const bfrag*)&sm[PSb + SWZ((16 * wv + l16) * 64 + tc * 32 + quad * 8, l16)];
#pragma unroll
            for (int kb = 0; kb < 8; kb++) {
                bfrag bg = *(const bfrag*)&sm[GT + SWZ((16 * kb + l16) * 64 + tc * 32 + quad * 8, l16)];
                O[kb] = MFMA16(ap, bg, O[kb]);
            }
        }

        // ---- ONE drain+barrier per iter; DMA had the whole compute to fly ----
        asm volatile("s_waitcnt vmcnt(0) lgkmcnt(0)" ::: "memory");
        __builtin_amdgcn_s_barrier();
    }
#undef STAGE_TILE

    // ---------------- Phase 2: reduce l; y -> YS; out = x + Wo*y + bo ----
    {
        float rs0 = l_r[0], rs1 = l_r[1], rs2 = l_r[2], rs3 = l_r[3];
#pragma unroll
        for (int m = 1; m <= 8; m <<= 1) {
            rs0 += __shfl_xor(rs0, m);
            rs1 += __shfl_xor(rs1, m);
            rs2 += __shfl_xor(rs2, m);
            rs3 += __shfl_xor(rs3, m);
        }
        float lr0 = 1.0f / rs0, lr1 = 1.0f / rs1, lr2 = 1.0f / rs2, lr3 = 1.0f / rs3;
#pragma unroll
        for (int kb = 0; kb < 8; kb++) {
            int rowb = 16 * wv + quad * 4;
            sm[QSb + SWZ((rowb + 0) * 128 + l16 + 16 * kb, rowb + 0)] = f2b(O[kb][0] * lr0);
            sm[QSb + SWZ((rowb + 1) * 128 + l16 + 16 * kb, rowb + 1)] = f2b(O[kb][1] * lr1);
            sm[QSb + SWZ((rowb + 2) * 128 + l16 + 16 * kb, rowb + 2)] = f2b(O[kb][2] * lr2);
            sm[QSb + SWZ((rowb + 3) * 128 + l16 + 16 * kb, rowb + 3)] = f2b(O[kb][3] * lr3);
        }
    }

#pragma unroll
    for (int qtr = 0; qtr < 4; qtr++) {
        __syncthreads();    // last-iter GT1 reads / prev WO reads done
        // stage Wo rows [qtr*64, qtr*64+64) bf16, swizzled [64][128]
#pragma unroll
        for (int i = 0; i < 8; i++) {
            int f = tid + i * 256;
            int c = f >> 5, ko = (f & 31) * 4;
            float4 w = *(const float4*)&Wo[(size_t)(qtr * 64 + c) * KCH + ko];
            ushort4 w4 = {f2b(w.x), f2b(w.y), f2b(w.z), f2b(w.w)};
            *(ushort4*)&sm[WOb + SWZ(c * 128 + ko, c)] = w4;
        }
        __syncthreads();

        ffrag zc[4];
#pragma unroll
        for (int cb = 0; cb < 4; cb++) zc[cb] = zf;
#pragma unroll
        for (int kc = 0; kc < 4; kc++) {
            bfrag ay = *(const bfrag*)&sm[QSb + SWZ((16 * wv + l16) * 128 + kc * 32 + quad * 8, l16)];
#pragma unroll
            for (int cb = 0; cb < 4; cb++) {
                bfrag bw = *(const bfrag*)&sm[WOb + SWZ((16 * cb + l16) * 128 + kc * 32 + quad * 8, l16)];
                zc[cb] = MFMA16(ay, bw, zc[cb]);
            }
        }
#pragma unroll
        for (int cb = 0; cb < 4; cb++) {
            int c = qtr * 64 + 16 * cb + l16;
            float bc = bo[c];
            size_t base = ((size_t)n * CCH + c) * SSP + q0 + 16 * wv + quad * 4;
            float4 xv = *(const float4*)&x[base];
            float4 ov;
            ov.x = xv.x + zc[cb][0] + bc;
            ov.y = xv.y + zc[cb][1] + bc;
            ov.z = xv.z + zc[cb][2] + bc;
            ov.w = xv.w + zc[cb][3] + bc;
            *(float4*)&out[base] = ov;
        }
    }
}

// ---------------------------------------------------------------------------
extern "C" void kernel_launch(void* const* d_in, const int* in_sizes, int n_in,
                              void* d_out, int out_size, void* d_ws, size_t ws_size,
                              hipStream_t stream) {
    const float* x  = (const float*)d_in[0];
    const float* Wg = (const float*)d_in[1];
    const float* bg = (const float*)d_in[2];
    const float* Wt = (const float*)d_in[3];
    const float* bt = (const float*)d_in[4];
    const float* Wp = (const float*)d_in[5];
    const float* bp = (const float*)d_in[6];
    const float* Wo = (const float*)d_in[7];
    const float* bo = (const float*)d_in[8];
    float* out = (float*)d_out;

    // ws: 16 MB total (verified-safe): G^T bf16 8MB + P bf16 8MB.
    u16* G = (u16*)d_ws;                       // [N,K,S] transposed
    u16* P = G + (size_t)NB * SSP * KCH;       // [N,S,K]

    proj_gp_kernel<<<dim3(NB * SSP / 64), 256, 0, stream>>>(x, Wg, bg, Wp, bp, G, P);
    attn_fused_kernel<<<dim3(NB * SSP / 64), 256, 0, stream>>>(x, Wt, bt, P, G, Wo, bo, out);
}

// Round 9
// 216.534 us; speedup vs baseline: 3.4010x; 1.0050x over previous
//
#include <hip/hip_runtime.h>
#include <hip/hip_bf16.h>

#define NB   8
#define CCH  256
#define KCH  128
#define SSP  4096

typedef unsigned short u16;
typedef __attribute__((ext_vector_type(8))) short  bfrag;  // 8 bf16 = 4 VGPRs
typedef __attribute__((ext_vector_type(4))) float  ffrag;  // 4 fp32 acc

#define MFMA16(a, b, c) __builtin_amdgcn_mfma_f32_16x16x32_bf16((a), (b), (c), 0, 0, 0)
// u16-index XOR swizzle: flips bits 3-5 (16B granule) by row&7 -> bank spread
#define SWZ(i, r) ((unsigned)(i) ^ ((((unsigned)(r)) & 7u) << 3))

// global -> LDS direct DMA, 16B per lane. LDS dest is WAVE-UNIFORM base
// (+lane*16 by HW); global src is PER-LANE (pre-swizzled => rule #21 combo:
// linear LDS dest + inverse-swizzled source + swizzled read).
#define GLDS(G, L) __builtin_amdgcn_global_load_lds(                          \
    (const __attribute__((address_space(1))) void*)(G),                       \
    (__attribute__((address_space(3))) void*)(L), 16, 0, 0)

__device__ __forceinline__ u16 f2b(float f) {            // fp32 -> bf16 RNE
    union { float f; unsigned u; } v; v.f = f;
    return (u16)((v.u + 0x7fffu + ((v.u >> 16) & 1u)) >> 16);
}

// ---------------------------------------------------------------------------
// K1: g and phi projections. Round-14 change: single raw barrier per chunk
// (lgkmcnt-only; vmcnt never force-drained — the commit's register reads
// carry the load dependency, so chunk-ahead loads fly a full chunk), LDS
// double-buffered (2 x 25.6 KB), loads issued 2 chunks ahead.
// ---------------------------------------------------------------------------
__global__ __launch_bounds__(256, 2) void proj_gp_kernel(
    const float* __restrict__ x,
    const float* __restrict__ Wg, const float* __restrict__ bg,
    const float* __restrict__ Wp, const float* __restrict__ bp,
    u16* __restrict__ G,   // [N,K,S] transposed
    u16* __restrict__ P)   // [N,S,K]
{
    __shared__ __align__(16) u16 sm[25600];     // 2 x 12800 (xs|wgs|wps)
    const int tid  = threadIdx.x;
    const int wv   = tid >> 6;
    const int lane = tid & 63;
    const int quad = lane >> 4, l16 = lane & 15;
    const int bid  = blockIdx.x;
    const int n  = bid & 7;
    const int s0 = (bid >> 3) * 64;

    const ffrag zf = {0.f, 0.f, 0.f, 0.f};
    ffrag ga[8], pa[8];
#pragma unroll
    for (int kb = 0; kb < 8; kb++) { ga[kb] = zf; pa[kb] = zf; }

    float4 xreg[2], wgreg[4], wpreg[4];

#define K1_LOAD(C0)                                                          \
    {                                                                        \
        _Pragma("unroll")                                                    \
        for (int i = 0; i < 2; i++) {                                        \
            int f = tid + i * 256;                                           \
            int c = f >> 4, s4 = (f & 15) * 4;                               \
            xreg[i] = *(const float4*)&x[((size_t)n * CCH + (C0) + c) * SSP + s0 + s4]; \
        }                                                                    \
        _Pragma("unroll")                                                    \
        for (int i = 0; i < 4; i++) {                                        \
            int f = tid + i * 256;                                           \
            int k = f >> 3, co = (f & 7) * 4;                                \
            wgreg[i] = *(const float4*)&Wg[k * CCH + (C0) + co];             \
            wpreg[i] = *(const float4*)&Wp[k * CCH + (C0) + co];             \
        }                                                                    \
    }

#define K1_COMMIT(B)                                                         \
    {                                                                        \
        const int bb = (B) * 12800;                                          \
        _Pragma("unroll")                                                    \
        for (int i = 0; i < 2; i++) {                                        \
            int f = tid + i * 256;                                           \
            int c = f >> 4, s4 = (f & 15) * 4;                               \
            sm[bb + (s4 + 0) * 40 + c] = f2b(xreg[i].x);                     \
            sm[bb + (s4 + 1) * 40 + c] = f2b(xreg[i].y);                     \
            sm[bb + (s4 + 2) * 40 + c] = f2b(xreg[i].z);                     \
            sm[bb + (s4 + 3) * 40 + c] = f2b(xreg[i].w);                     \
        }                                                                    \
        _Pragma("unroll")                                                    \
        for (int i = 0; i < 4; i++) {                                        \
            int f = tid + i * 256;                                           \
            int k = f >> 3, co = (f & 7) * 4;                                \
            ushort4 g4 = {f2b(wgreg[i].x), f2b(wgreg[i].y), f2b(wgreg[i].z), f2b(wgreg[i].w)}; \
            ushort4 p4 = {f2b(wpreg[i].x), f2b(wpreg[i].y), f2b(wpreg[i].z), f2b(wpreg[i].w)}; \
            *(ushort4*)&sm[bb + 2560 + k * 40 + co] = g4;                    \
            *(ushort4*)&sm[bb + 7680 + k * 40 + co] = p4;                    \
        }                                                                    \
    }

    // prologue: chunk0 -> buf0; chunk1 loads in flight
    K1_LOAD(0)
    K1_COMMIT(0)
    K1_LOAD(32)
    asm volatile("s_waitcnt lgkmcnt(0)" ::: "memory");
    __builtin_amdgcn_s_barrier();

#pragma unroll
    for (int it = 0; it < 8; ++it) {
        if (it < 7) K1_COMMIT((it + 1) & 1)         // chunk it+1 -> idle buf
        if (it < 6) K1_LOAD((it + 2) * 32)          // fly across the barrier
        const int bb = (it & 1) * 12800;
        bfrag a = *(const bfrag*)&sm[bb + (16 * wv + l16) * 40 + quad * 8];
#pragma unroll
        for (int kb = 0; kb < 8; kb++) {
            bfrag bgf = *(const bfrag*)&sm[bb + 2560 + (16 * kb + l16) * 40 + quad * 8];
            bfrag bpf = *(const bfrag*)&sm[bb + 7680 + (16 * kb + l16) * 40 + quad * 8];
            ga[kb] = MFMA16(a, bgf, ga[kb]);
            pa[kb] = MFMA16(a, bpf, pa[kb]);
        }
        asm volatile("s_waitcnt lgkmcnt(0)" ::: "memory");
        __builtin_amdgcn_s_barrier();
    }
#undef K1_LOAD
#undef K1_COMMIT

#pragma unroll
    for (int kb = 0; kb < 8; kb++) {
        int k = l16 + 16 * kb;
        float bgv = bg[k], bpv = bp[k];
        int srow = s0 + 16 * wv + quad * 4;
        ushort4 g4 = {f2b(ga[kb][0] + bgv), f2b(ga[kb][1] + bgv),
                      f2b(ga[kb][2] + bgv), f2b(ga[kb][3] + bgv)};
        *(ushort4*)&G[(size_t)n * KCH * SSP + (size_t)k * SSP + srow] = g4;
#pragma unroll
        for (int r = 0; r < 4; r++)
            P[((size_t)n * SSP + srow + r) * KCH + k] = f2b(pa[kb][r] + bpv);
    }
}

// ---------------------------------------------------------------------------
// K2: fused theta-proj + flash attention + out-proj, all MFMA.
// Round-14 vs round 8 (attn was LDS-op-throughput-bound: 34 b128 reads/wave/
// iter ~ 80% of cycle budget): 32q x 32t wave tiling.
//   wq = wv&1 (q-half), tpar = wv>>1 (t-half). Each wave: 2 q-blocks x own
//   32-t half; K=32 MFMAs consume the full half per instruction.
//   Reads/wave/iter: QK 8 + PS-A 2 + PV-G 8 = 18 (was 34); MFMAs 32 (same).
//   O,l additive over t (no running max) -> one post-loop combine across
//   t-parity pairs through the retired KS region (fp32) + PS (l).
// Staging (DMA, pre-swizzled source), LDS map, sync structure: round 8.
// LDS map (u16 idx, 36864 = 72 KB, 2 blocks/CU):
//   KS0@0 KS1@8192 GT0@16384 GT1@24576 PS@32768
//   aliases: XT@8192+WT@10752 / QS@8192 (phase 0, = KS1); post-loop:
//   O-exch fp32 @ words 0..8191 (KS0+KS1), l-exch fp32 @ words 16384.. (PS),
//   YS@GT1, WO@GT0 (epilogue).
// ---------------------------------------------------------------------------
__global__ __launch_bounds__(256, 2) void attn_fused_kernel(
    const float* __restrict__ x,
    const float* __restrict__ Wt, const float* __restrict__ bt,
    const u16* __restrict__ Pb,   // phi rows bf16 [N,S,K]
    const u16* __restrict__ Gt,   // g bf16 TRANSPOSED [N,K,S]
    const float* __restrict__ Wo, const float* __restrict__ bo,
    float* __restrict__ out)
{
    __shared__ __align__(16) u16 sm[36864];     // 72 KB
    const int tid  = threadIdx.x;
    const int wv   = tid >> 6;                  // 0..3
    const int lane = tid & 63;
    const int quad = lane >> 4, l16 = lane & 15;
    const int wq   = wv & 1;                    // q-half (32 rows)
    const int tpar = wv >> 1;                   // t-half (32 cols)
    const int bid  = blockIdx.x;
    const int n    = bid & 7;
    const int q0   = (bid >> 3) * 64;
    // 1/sqrt(128) * log2(e): exp(s*scale) == exp2(s*qscale)
    const float qscale = 0.08838834764831845f * 1.4426950408889634f;
    const ffrag zf = {0.f, 0.f, 0.f, 0.f};

    const int KS0b = 0, KS1b = 8192, GT0b = 16384, GT1b = 24576, PSb = 32768;
    const int XTb = 8192, WTb = 10752, QSb = 8192;
    const int YSb = 24576, WOb = 16384;          // epilogue aliases

    const u16* Pbase = Pb + (size_t)n * SSP * KCH;
    const u16* Gbase = Gt + (size_t)n * KCH * SSP;

#define STAGE_TILE(KSw, GTw, T0)                                             \
    {                                                                        \
        _Pragma("unroll")                                                    \
        for (int i = 0; i < 4; i++) {                                        \
            int chunk = wv * 4 + i;                                          \
            int row = chunk * 4 + (lane >> 4);                               \
            int cs  = ((lane & 15) * 8) ^ ((row & 7) << 3);                  \
            GLDS(Pbase + (size_t)((T0) + row) * KCH + cs,                    \
                 &sm[(KSw) + chunk * 512]);                                  \
        }                                                                    \
        _Pragma("unroll")                                                    \
        for (int i = 0; i < 4; i++) {                                        \
            int chunk = wv * 4 + i;                                          \
            int k  = chunk * 8 + (lane >> 3);                                \
            int cs = ((lane & 7) * 8) ^ ((k & 7) << 3);                      \
            GLDS(Gbase + (size_t)k * SSP + (T0) + cs,                        \
                 &sm[(GTw) + chunk * 512]);                                  \
        }                                                                    \
    }

    // ---- tile 0 -> buf0 DMA issued NOW; flies under phase 0 ----
    STAGE_TILE(KS0b, GT0b, 0)

    // ---------------- Phase 0: Qs = (theta(x)+bt)*qscale, bf16 ----------------
    {
        ffrag qa[8];
#pragma unroll
        for (int kb = 0; kb < 8; kb++) qa[kb] = zf;

        for (int c0 = 0; c0 < CCH; c0 += 32) {
#pragma unroll
            for (int i = 0; i < 2; i++) {
                int f = tid + i * 256;
                int c = f >> 4, s4 = (f & 15) * 4;
                float4 xv = *(const float4*)&x[((size_t)n * CCH + c0 + c) * SSP + q0 + s4];
                sm[XTb + (s4 + 0) * 40 + c] = f2b(xv.x);
                sm[XTb + (s4 + 1) * 40 + c] = f2b(xv.y);
                sm[XTb + (s4 + 2) * 40 + c] = f2b(xv.z);
                sm[XTb + (s4 + 3) * 40 + c] = f2b(xv.w);
            }
#pragma unroll
            for (int i = 0; i < 4; i++) {
                int f = tid + i * 256;
                int k = f >> 3, co = (f & 7) * 4;
                float4 wq4 = *(const float4*)&Wt[k * CCH + c0 + co];
                ushort4 q4 = {f2b(wq4.x), f2b(wq4.y), f2b(wq4.z), f2b(wq4.w)};
                *(ushort4*)&sm[WTb + k * 40 + co] = q4;
            }
            __syncthreads();
            bfrag aq = *(const bfrag*)&sm[XTb + (16 * wv + l16) * 40 + quad * 8];
#pragma unroll
            for (int kb = 0; kb < 8; kb++) {
                bfrag bw = *(const bfrag*)&sm[WTb + (16 * kb + l16) * 40 + quad * 8];
                qa[kb] = MFMA16(aq, bw, qa[kb]);
            }
            __syncthreads();
        }
#pragma unroll
        for (int kb = 0; kb < 8; kb++) {
            float btv = bt[l16 + 16 * kb];
#pragma unroll
            for (int r = 0; r < 4; r++) {
                int row = 16 * wv + quad * 4 + r;
                sm[QSb + SWZ(row * 128 + l16 + 16 * kb, row)] = f2b((qa[kb][r] + btv) * qscale);
            }
        }
    }
    __syncthreads();    // qf hoist below is CROSS-WAVE (wq-based rows)

    // ---- hoist Q A-fragments: wave (wq,tpar) owns q-rows [32wq, 32wq+32) ----
    bfrag qf[2][4];
#pragma unroll
    for (int qb = 0; qb < 2; qb++)
#pragma unroll
        for (int kc = 0; kc < 4; kc++)
            qf[qb][kc] = *(const bfrag*)&sm[QSb + SWZ((32 * wq + 16 * qb + l16) * 128 + kc * 32 + quad * 8, l16)];

    // ---- prologue sync: tile-0 DMA visible, QS reads retired ----
    asm volatile("s_waitcnt vmcnt(0) lgkmcnt(0)" ::: "memory");
    __builtin_amdgcn_s_barrier();

    // ---------------- Phase 1: flash attention over t-tiles ----------------
    ffrag O[2][8];
#pragma unroll
    for (int qb = 0; qb < 2; qb++)
#pragma unroll
        for (int kb = 0; kb < 8; kb++) O[qb][kb] = zf;
    float l_r[2][4];
#pragma unroll
    for (int qb = 0; qb < 2; qb++)
#pragma unroll
        for (int r = 0; r < 4; r++) l_r[qb][r] = 0.f;

    const int NT = SSP / 64;        // 64 tiles
#pragma unroll 2
    for (int it = 0; it < NT; ++it) {
        const int cur = it & 1;
        const int KS  = cur ? KS1b : KS0b;
        const int GT  = cur ? GT1b : GT0b;

        // ---- issue tile it+1 DMA into the idle buffer ----
        if (it + 1 < NT) {
            const int KSw = cur ? KS0b : KS1b;
            const int GTw = cur ? GT0b : GT1b;
            STAGE_TILE(KSw, GTw, (it + 1) * 64)
        }

        // ---- QK^T on own 32-t half (B-frags shared across 2 q-blocks) ----
        ffrag sa[2][2];
#pragma unroll
        for (int qb = 0; qb < 2; qb++)
#pragma unroll
            for (int tb = 0; tb < 2; tb++) sa[qb][tb] = zf;
#pragma unroll
        for (int kc = 0; kc < 4; kc++)
#pragma unroll
            for (int tb = 0; tb < 2; tb++) {
                bfrag bk = *(const bfrag*)&sm[KS + SWZ((16 * (2 * tpar + tb) + l16) * 128 + kc * 32 + quad * 8, l16)];
                sa[0][tb] = MFMA16(qf[0][kc], bk, sa[0][tb]);
                sa[1][tb] = MFMA16(qf[1][kc], bk, sa[1][tb]);
            }

        // ---- softmax numerator; l accumulated per-lane ----
#pragma unroll
        for (int qb = 0; qb < 2; qb++)
#pragma unroll
            for (int r = 0; r < 4; r++) {
                float p0 = __builtin_amdgcn_exp2f(sa[qb][0][r]);
                float p1 = __builtin_amdgcn_exp2f(sa[qb][1][r]);
                l_r[qb][r] += p0 + p1;
                int row = 32 * wq + 16 * qb + quad * 4 + r;
                int cb0 = row * 64 + l16 + 32 * tpar;
                sm[PSb + SWZ(cb0,      row)] = f2b(p0);
                sm[PSb + SWZ(cb0 + 16, row)] = f2b(p1);
            }
        // PS rows x own-cols are wave-private: in-wave ordering suffices.

        // ---- PV: O += P * G over own 32-t half (K=32: one MFMA per kb) ----
        {
            bfrag ap0 = *(const bfrag*)&sm[PSb + SWZ((32 * wq + l16) * 64 + 32 * tpar + quad * 8, l16)];
            bfrag ap1 = *(const bfrag*)&sm[PSb + SWZ((32 * wq + 16 + l16) * 64 + 32 * tpar + quad * 8, l16)];
#pragma unroll
            for (int kb = 0; kb < 8; kb++) {
                bfrag bg = *(const bfrag*)&sm[GT + SWZ((16 * kb + l16) * 64 + 32 * tpar + quad * 8, l16)];
                O[0][kb] = MFMA16(ap0, bg, O[0][kb]);
                O[1][kb] = MFMA16(ap1, bg, O[1][kb]);
            }
        }

        // ---- ONE drain+barrier per iter ----
        asm volatile("s_waitcnt vmcnt(0) lgkmcnt(0)" ::: "memory");
        __builtin_amdgcn_s_barrier();
    }
#undef STAGE_TILE

    // ---------------- combine t-parity partials; y -> YS ----------------
#pragma unroll
    for (int qb = 0; qb < 2; qb++)
#pragma unroll
        for (int r = 0; r < 4; r++) {
            float rs = l_r[qb][r];
#pragma unroll
            for (int m = 1; m <= 8; m <<= 1) rs += __shfl_xor(rs, m);
            l_r[qb][r] = rs;            // own-half l, uniform across l16
        }
    float* smf = (float*)sm;
    if (tpar == 1) {
#pragma unroll
        for (int qb = 0; qb < 2; qb++)
#pragma unroll
            for (int kb = 0; kb < 8; kb++)
#pragma unroll
                for (int r = 0; r < 4; r++) {
                    int row = 32 * wq + 16 * qb + quad * 4 + r;
                    smf[row * 128 + 16 * kb + l16] = O[qb][kb][r];
                }
        if (l16 == 0) {
#pragma unroll
            for (int qb = 0; qb < 2; qb++)
#pragma unroll
                for (int r = 0; r < 4; r++)
                    smf[16384 + 32 * wq + 16 * qb + quad * 4 + r] = l_r[qb][r];
        }
    }
    __syncthreads();
    if (tpar == 0) {
#pragma unroll
        for (int qb = 0; qb < 2; qb++)
#pragma unroll
            for (int r = 0; r < 4; r++) {
                int row = 32 * wq + 16 * qb + quad * 4 + r;
                float linv = 1.0f / (l_r[qb][r] + smf[16384 + row]);
#pragma unroll
                for (int kb = 0; kb < 8; kb++) {
                    int col = 16 * kb + l16;
                    float o = O[qb][kb][r] + smf[row * 128 + col];
                    sm[YSb + SWZ(row * 128 + col, row)] = f2b(o * linv);
                }
            }
    }

    // ---------------- Phase 2: out = x + Wo*y + bo ----------------
#pragma unroll
    for (int qtr = 0; qtr < 4; qtr++) {
        __syncthreads();    // YS visible / prev WO reads done
        // stage Wo rows [qtr*64, qtr*64+64) bf16, swizzled [64][128] @ GT0
#pragma unroll
        for (int i = 0; i < 8; i++) {
            int f = tid + i * 256;
            int c = f >> 5, ko = (f & 31) * 4;
            float4 w = *(const float4*)&Wo[(size_t)(qtr * 64 + c) * KCH + ko];
            ushort4 w4 = {f2b(w.x), f2b(w.y), f2b(w.z), f2b(w.w)};
            *(ushort4*)&sm[WOb + SWZ(c * 128 + ko, c)] = w4;
        }
        __syncthreads();

        ffrag zc[4];
#pragma unroll
        for (int cb = 0; cb < 4; cb++) zc[cb] = zf;
#pragma unroll
        for (int kc = 0; kc < 4; kc++) {
            bfrag ay = *(const bfrag*)&sm[YSb + SWZ((16 * wv + l16) * 128 + kc * 32 + quad * 8, l16)];
#pragma unroll
            for (int cb = 0; cb < 4; cb++) {
                bfrag bw = *(const bfrag*)&sm[WOb + SWZ((16 * cb + l16) * 128 + kc * 32 + quad * 8, l16)];
                zc[cb] = MFMA16(ay, bw, zc[cb]);
            }
        }
#pragma unroll
        for (int cb = 0; cb < 4; cb++) {
            int c = qtr * 64 + 16 * cb + l16;
            float bc = bo[c];
            size_t base = ((size_t)n * CCH + c) * SSP + q0 + 16 * wv + quad * 4;
            float4 xv = *(const float4*)&x[base];
            float4 ov;
            ov.x = xv.x + zc[cb][0] + bc;
            ov.y = xv.y + zc[cb][1] + bc;
            ov.z = xv.z + zc[cb][2] + bc;
            ov.w = xv.w + zc[cb][3] + bc;
            *(float4*)&out[base] = ov;
        }
    }
}

// ---------------------------------------------------------------------------
extern "C" void kernel_launch(void* const* d_in, const int* in_sizes, int n_in,
                              void* d_out, int out_size, void* d_ws, size_t ws_size,
                              hipStream_t stream) {
    const float* x  = (const float*)d_in[0];
    const float* Wg = (const float*)d_in[1];
    const float* bg = (const float*)d_in[2];
    const float* Wt = (const float*)d_in[3];
    const float* bt = (const float*)d_in[4];
    const float* Wp = (const float*)d_in[5];
    const float* bp = (const float*)d_in[6];
    const float* Wo = (const float*)d_in[7];
    const float* bo = (const float*)d_in[8];
    float* out = (float*)d_out;

    // ws: 16 MB total (verified-safe): G^T bf16 8MB + P bf16 8MB.
    u16* G = (u16*)d_ws;                       // [N,K,S] transposed
    u16* P = G + (size_t)NB * SSP * KCH;       // [N,S,K]

    proj_gp_kernel<<<dim3(NB * SSP / 64), 256, 0, stream>>>(x, Wg, bg, Wp, bp, G, P);
    attn_fused_kernel<<<dim3(NB * SSP / 64), 256, 0, stream>>>(x, Wt, bt, P, G, Wo, bo, out);
}